// Round 1
// baseline (29426.352 us; speedup 1.0000x reference)
//
#include <hip/hip_runtime.h>
#include <cmath>

#define NPTS 4096
#define DIM  64
#define TI   64
#define TJ   64

// norms[0][b][i] = 0.5*|x_i|^2 ; norms[1][b][i] = 0.5*|y_i|^2
__global__ __launch_bounds__(256) void norms_kernel(const float* __restrict__ x,
                                                    const float* __restrict__ y,
                                                    float* __restrict__ norms) {
    int flat = blockIdx.x * 256 + threadIdx.x;   // 0..32767
    int which = flat >> 14;                       // 0: x, 1: y
    int rem = flat & 16383;
    int b = rem >> 12;
    int i = rem & 4095;
    const float* p = (which ? y : x) + (size_t)b * DIM * NPTS + i;
    float s = 0.f;
#pragma unroll
    for (int c = 0; c < DIM; ++c) {
        float v = p[(size_t)c * NPTS];
        s += v * v;
    }
    norms[flat] = 0.5f * s;
}

// One annealing phase: updates all 4 potentials for all 4 batches.
//   mat 0: f_ba  rows=x cols=y  h from prev g_ab (prev[1])
//   mat 1: g_ab  rows=y cols=x  h from prev f_ba (prev[0])
//   mat 2: f_aa  rows=x cols=x  h from prev f_aa (prev[2])
//   mat 3: g_bb  rows=y cols=y  h from prev g_bb (prev[3])
// out[i] = rownorm[i] - eps*(m + log l); avg mode: 0.5*(prev[mat][i] + out)
__global__ __launch_bounds__(256) void softmin_kernel(
    const float* __restrict__ x, const float* __restrict__ y,
    const float* __restrict__ norms,
    const float* __restrict__ prev, float* __restrict__ next,
    float eps, int use_prev, int do_avg)
{
    __shared__ float xs[DIM][TI];    // [c][ii]
    __shared__ float ys[DIM][TJ];    // [c][jj]
    __shared__ float hs[TJ];

    const int tid   = threadIdx.x;
    const int bid   = blockIdx.x;
    const int itile = bid & 63;
    const int mat   = (bid >> 6) & 3;
    const int b     = bid >> 8;

    const int row_is_x = (mat == 0 || mat == 2);
    const int col_is_x = (mat == 1 || mat == 2);
    const float* rowpts  = (row_is_x ? x : y) + (size_t)b * DIM * NPTS;
    const float* colpts  = (col_is_x ? x : y) + (size_t)b * DIM * NPTS;
    const float* rownorm = norms + (row_is_x ? 0 : 16384) + b * NPTS;
    const float* colnorm = norms + (col_is_x ? 0 : 16384) + b * NPTS;
    const int hmat = (mat == 0) ? 1 : ((mat == 1) ? 0 : mat);
    const float* hvec   = prev + (size_t)(hmat * 4 + b) * NPTS;
    const float* avgvec = prev + (size_t)(mat  * 4 + b) * NPTS;
    float*       outvec = next + (size_t)(mat  * 4 + b) * NPTS;

    const float inv_eps = 1.0f / eps;
    const float wlog    = -logf(4096.0f);
    const int   i0      = itile * TI;

    // stage row tile once: xs[c][ii] = rowpts[c*NPTS + i0 + ii]
#pragma unroll
    for (int k = 0; k < 4; ++k) {
        int idx = tid + k * 256;            // float4 slot 0..1023
        int c = idx >> 4;
        int q = idx & 15;
        float4 v = *(const float4*)(rowpts + (size_t)c * NPTS + i0 + q * 4);
        *(float4*)(&xs[c][q * 4]) = v;
    }

    const int rg = tid >> 4;   // row group 0..15  (rows i0 + rg*4 .. +3)
    const int cg = tid & 15;   // col group 0..15  (cols j0 + cg*4 .. +3)

    float m[4], l[4];
#pragma unroll
    for (int r = 0; r < 4; ++r) { m[r] = -INFINITY; l[r] = 0.f; }

    for (int jt = 0; jt < NPTS / TJ; ++jt) {
        const int j0 = jt * TJ;
        __syncthreads();                      // protect ys/hs readers
#pragma unroll
        for (int k = 0; k < 4; ++k) {
            int idx = tid + k * 256;
            int c = idx >> 4;
            int q = idx & 15;
            float4 v = *(const float4*)(colpts + (size_t)c * NPTS + j0 + q * 4);
            *(float4*)(&ys[c][q * 4]) = v;
        }
        if (tid < TJ) {
            int j = j0 + tid;
            float hv = wlog - colnorm[j] * inv_eps;
            if (use_prev) hv += hvec[j] * inv_eps;
            hs[tid] = hv;
        }
        __syncthreads();

        float acc[4][4];
#pragma unroll
        for (int r = 0; r < 4; ++r)
#pragma unroll
            for (int q = 0; q < 4; ++q) acc[r][q] = 0.f;

#pragma unroll 16
        for (int c = 0; c < DIM; ++c) {
            float4 xv = *(const float4*)(&xs[c][rg * 4]);
            float4 yv = *(const float4*)(&ys[c][cg * 4]);
            acc[0][0] = fmaf(xv.x, yv.x, acc[0][0]);
            acc[0][1] = fmaf(xv.x, yv.y, acc[0][1]);
            acc[0][2] = fmaf(xv.x, yv.z, acc[0][2]);
            acc[0][3] = fmaf(xv.x, yv.w, acc[0][3]);
            acc[1][0] = fmaf(xv.y, yv.x, acc[1][0]);
            acc[1][1] = fmaf(xv.y, yv.y, acc[1][1]);
            acc[1][2] = fmaf(xv.y, yv.z, acc[1][2]);
            acc[1][3] = fmaf(xv.y, yv.w, acc[1][3]);
            acc[2][0] = fmaf(xv.z, yv.x, acc[2][0]);
            acc[2][1] = fmaf(xv.z, yv.y, acc[2][1]);
            acc[2][2] = fmaf(xv.z, yv.z, acc[2][2]);
            acc[2][3] = fmaf(xv.z, yv.w, acc[2][3]);
            acc[3][0] = fmaf(xv.w, yv.x, acc[3][0]);
            acc[3][1] = fmaf(xv.w, yv.y, acc[3][1]);
            acc[3][2] = fmaf(xv.w, yv.z, acc[3][2]);
            acc[3][3] = fmaf(xv.w, yv.w, acc[3][3]);
        }

        float h0 = hs[cg * 4 + 0], h1 = hs[cg * 4 + 1];
        float h2 = hs[cg * 4 + 2], h3 = hs[cg * 4 + 3];
#pragma unroll
        for (int r = 0; r < 4; ++r) {
            float s0 = fmaf(acc[r][0], inv_eps, h0);
            float s1 = fmaf(acc[r][1], inv_eps, h1);
            float s2 = fmaf(acc[r][2], inv_eps, h2);
            float s3 = fmaf(acc[r][3], inv_eps, h3);
            float tm = fmaxf(fmaxf(s0, s1), fmaxf(s2, s3));
            float mn = fmaxf(m[r], tm);
            float lsum = l[r] * __expf(m[r] - mn);
            lsum += __expf(s0 - mn) + __expf(s1 - mn)
                  + __expf(s2 - mn) + __expf(s3 - mn);
            m[r] = mn; l[r] = lsum;
        }
    }

    // merge the 16 col-groups sharing each row (lanes differing in bits 0..3)
#pragma unroll
    for (int off = 1; off < 16; off <<= 1) {
#pragma unroll
        for (int r = 0; r < 4; ++r) {
            float mo = __shfl_xor(m[r], off);
            float lo = __shfl_xor(l[r], off);
            float mn = fmaxf(m[r], mo);
            l[r] = l[r] * __expf(m[r] - mn) + lo * __expf(mo - mn);
            m[r] = mn;
        }
    }

    if (cg == 0) {
#pragma unroll
        for (int r = 0; r < 4; ++r) {
            int i = i0 + rg * 4 + r;
            float f = rownorm[i] - eps * (m[r] + logf(l[r]));
            if (do_avg) f = 0.5f * (avgvec[i] + f);
            outvec[i] = f;
        }
    }
}

// loss = sum_{b,i} (f_ba - f_aa) + (g_ab - g_bb), scaled by 1/(N*B)
__global__ __launch_bounds__(256) void reduce_kernel(const float* __restrict__ fin,
                                                     float* __restrict__ out) {
    float s = 0.f;
    for (int idx = threadIdx.x; idx < 4 * 4 * NPTS; idx += 256) {
        int mat = idx >> 14;
        float v = fin[idx];
        s += (mat < 2) ? v : -v;
    }
#pragma unroll
    for (int off = 32; off > 0; off >>= 1) s += __shfl_down(s, off);
    __shared__ float red[4];
    if ((threadIdx.x & 63) == 0) red[threadIdx.x >> 6] = s;
    __syncthreads();
    if (threadIdx.x == 0) {
        float t = red[0] + red[1] + red[2] + red[3];
        out[0] = t * (1.0f / (4096.0f * 4.0f));
    }
}

extern "C" void kernel_launch(void* const* d_in, const int* in_sizes, int n_in,
                              void* d_out, int out_size, void* d_ws, size_t ws_size,
                              hipStream_t stream) {
    const float* x = (const float*)d_in[0];
    const float* y = (const float*)d_in[1];
    float* out = (float*)d_out;

    float* norms = (float*)d_ws;          // 32768 floats
    float* bufA  = norms + 32768;         // 65536 floats: [mat][b][i]
    float* bufB  = bufA + 65536;          // 65536 floats

    // eps schedule: exp(arange(2*ln16, 2*ln0.05, 2*ln0.9)) ++ [0.05^2]
    const double start = 2.0 * log(16.0);
    const double stop  = 2.0 * log(0.05);
    const double step  = 2.0 * log(0.9);
    float eps_list[64];
    int ne = 0;
    for (int k = 0;; ++k) {
        double e = start + k * step;
        if (!(e > stop)) break;
        eps_list[ne++] = (float)exp(e);
    }
    eps_list[ne++] = (float)(0.05 * 0.05);   // 56 entries total

    norms_kernel<<<128, 256, 0, stream>>>(x, y, norms);

    // init at eps0 (no prev potentials)
    softmin_kernel<<<1024, 256, 0, stream>>>(x, y, norms, bufB, bufA,
                                             eps_list[0], 0, 1 == 2);
    float* prev = bufA;
    float* next = bufB;
    // 56 averaged scan steps
    for (int t = 0; t < ne; ++t) {
        softmin_kernel<<<1024, 256, 0, stream>>>(x, y, norms, prev, next,
                                                 eps_list[t], 1, 1);
        float* tmp = prev; prev = next; next = tmp;
    }
    // final extrapolation at eps = blur^p, no averaging
    softmin_kernel<<<1024, 256, 0, stream>>>(x, y, norms, prev, next,
                                             eps_list[ne - 1], 1, 0);

    reduce_kernel<<<1, 256, 0, stream>>>(next, out);
}

// Round 2
// 11516.711 us; speedup vs baseline: 2.5551x; 2.5551x over previous
//
#include <hip/hip_runtime.h>
#include <cmath>

#define NPTS 4096
#define LOG2E_F 1.4426950408889634f
#define LN2_F   0.6931471805599453f
#define BLOG_F  -8.31776616671934f   /* -ln(4096) */

typedef __attribute__((ext_vector_type(8)))  short s16x8;
typedef __attribute__((ext_vector_type(16))) float f32x16;

__device__ __forceinline__ ushort bf16h(float f) {
    uint u = __float_as_uint(f);
    return (ushort)((u + 0x7fffu + ((u >> 16) & 1u)) >> 16);
}
__device__ __forceinline__ float bf16tof(ushort h) {
    return __uint_as_float(((uint)h) << 16);
}

// norms[0][b][i] = 0.5*|x_i|^2 ; norms[1][b][i] = 0.5*|y_i|^2
__global__ __launch_bounds__(256) void norms_kernel(const float* __restrict__ x,
                                                    const float* __restrict__ y,
                                                    float* __restrict__ norms) {
    int flat = blockIdx.x * 256 + threadIdx.x;   // 0..32767
    int which = flat >> 14;
    int rem = flat & 16383;
    int b = rem >> 12;
    int i = rem & 4095;
    const float* p = (which ? y : x) + (size_t)b * 64 * NPTS + i;
    float s = 0.f;
#pragma unroll
    for (int c = 0; c < 64; ++c) {
        float v = p[(size_t)c * NPTS];
        s += v * v;
    }
    norms[flat] = 0.5f * s;
}

// One annealing phase. Split-bf16 MFMA for the Gram term:
//   u_ij = h2_j + dot_ij * se,  se = log2e/eps
//   h2_j = blog*log2e + (g_j - yn_j)*se
//   f_i  = xn_i - eps*ln2*(m_i + log2 l_i)
// mat 0: f_ba rows=x cols=y (h from prev[1]);  1: g_ab rows=y cols=x (prev[0])
// mat 2: f_aa rows=x cols=x (prev[2]);         3: g_bb rows=y cols=y (prev[3])
__global__ __launch_bounds__(256, 2) void softmin_kernel(
    const float* __restrict__ x, const float* __restrict__ y,
    const float* __restrict__ norms,
    const float* __restrict__ prev, float* __restrict__ next,
    float eps, int use_prev, int do_avg)
{
    __shared__ ushort Bhi[128][72];   // [col n][component c], 144 B row stride
    __shared__ ushort Blo[128][72];

    const int tid   = threadIdx.x;
    const int bid   = blockIdx.x;
    // XCD-friendly decode: consecutive bids (round-robin over 8 XCDs) keep
    // b = bid&3 constant per XCD -> each XCD's L2 holds one batch (2 MB).
    const int b     = bid & 3;
    const int mat   = (bid >> 2) & 3;
    const int itile = bid >> 4;           // 0..31

    const int row_is_x = (mat == 0 || mat == 2);
    const int col_is_x = (mat == 1 || mat == 2);
    const float* rowpts  = (row_is_x ? x : y) + (size_t)b * 64 * NPTS;
    const float* colpts  = (col_is_x ? x : y) + (size_t)b * 64 * NPTS;
    const float* rownorm = norms + (row_is_x ? 0 : 16384) + b * NPTS;
    const float* colnorm = norms + (col_is_x ? 0 : 16384) + b * NPTS;
    const int hmat = (mat == 0) ? 1 : ((mat == 1) ? 0 : mat);
    const float* hvec   = prev + (size_t)(hmat * 4 + b) * NPTS;
    const float* avgvec = prev + (size_t)(mat  * 4 + b) * NPTS;
    float*       outvec = next + (size_t)(mat  * 4 + b) * NPTS;

    const float inv_eps = 1.0f / eps;
    const float se  = inv_eps * LOG2E_F;
    const float h2c = BLOG_F * LOG2E_F;

    const int wave  = tid >> 6;    // row strip 0..3
    const int lane  = tid & 63;
    const int lrow  = lane & 31;   // MFMA row (A) / col (B) lane
    const int lhalf = lane >> 5;   // k-half select

    const int i0   = itile * 128;
    const int arow = i0 + wave * 32 + lrow;

    // ---- A fragments: direct global->register, hi/lo split, once per block
    s16x8 ah[4], al[4];
#pragma unroll
    for (int kc = 0; kc < 4; ++kc) {
#pragma unroll
        for (int e = 0; e < 8; ++e) {
            int c = kc * 16 + lhalf * 8 + e;
            float v = rowpts[(size_t)c * NPTS + arow];
            ushort h = bf16h(v);
            float lo = v - bf16tof(h);
            ah[kc][e] = (short)h;
            al[kc][e] = (short)bf16h(lo);
        }
    }

    float m[16], l[16];
#pragma unroll
    for (int r = 0; r < 16; ++r) { m[r] = -__builtin_inff(); l[r] = 0.f; }

    for (int jt = 0; jt < 32; ++jt) {
        const int j0 = jt * 128;
        __syncthreads();
        // ---- stage B tile (128 cols x 64 comps) as bf16 hi/lo, transposed
#pragma unroll
        for (int it = 0; it < 8; ++it) {
            int slot = it * 256 + tid;        // 0..2047
            int n  = slot & 127;
            int c4 = (slot >> 7) * 4;         // 0,4,...,60
            const float* p = colpts + (size_t)c4 * NPTS + (j0 + n);
            float f0 = p[0 * NPTS], f1 = p[1 * NPTS];
            float f2 = p[2 * NPTS], f3 = p[3 * NPTS];
            ushort h0 = bf16h(f0), h1 = bf16h(f1), h2_ = bf16h(f2), h3 = bf16h(f3);
            ushort g0 = bf16h(f0 - bf16tof(h0));
            ushort g1 = bf16h(f1 - bf16tof(h1));
            ushort g2 = bf16h(f2 - bf16tof(h2_));
            ushort g3 = bf16h(f3 - bf16tof(h3));
            uint2 hw, lw;
            hw.x = (uint)h0 | ((uint)h1 << 16);
            hw.y = (uint)h2_ | ((uint)h3 << 16);
            lw.x = (uint)g0 | ((uint)g1 << 16);
            lw.y = (uint)g2 | ((uint)g3 << 16);
            *(uint2*)&Bhi[n][c4] = hw;
            *(uint2*)&Blo[n][c4] = lw;
        }
        __syncthreads();

        // ---- 4 col-tiles, processed as 2 pairs (shared online-softmax update)
#pragma unroll
        for (int cp = 0; cp < 2; ++cp) {
            f32x16 acc0 = (f32x16)0.0f, acc1 = (f32x16)0.0f;
#pragma unroll
            for (int kc = 0; kc < 4; ++kc) {
                const int coff = kc * 16 + lhalf * 8;
                s16x8 b0h = *(const s16x8*)&Bhi[(cp * 2 + 0) * 32 + lrow][coff];
                s16x8 b0l = *(const s16x8*)&Blo[(cp * 2 + 0) * 32 + lrow][coff];
                s16x8 b1h = *(const s16x8*)&Bhi[(cp * 2 + 1) * 32 + lrow][coff];
                s16x8 b1l = *(const s16x8*)&Blo[(cp * 2 + 1) * 32 + lrow][coff];
                acc0 = __builtin_amdgcn_mfma_f32_32x32x16_bf16(ah[kc], b0h, acc0, 0, 0, 0);
                acc0 = __builtin_amdgcn_mfma_f32_32x32x16_bf16(ah[kc], b0l, acc0, 0, 0, 0);
                acc0 = __builtin_amdgcn_mfma_f32_32x32x16_bf16(al[kc], b0h, acc0, 0, 0, 0);
                acc1 = __builtin_amdgcn_mfma_f32_32x32x16_bf16(ah[kc], b1h, acc1, 0, 0, 0);
                acc1 = __builtin_amdgcn_mfma_f32_32x32x16_bf16(ah[kc], b1l, acc1, 0, 0, 0);
                acc1 = __builtin_amdgcn_mfma_f32_32x32x16_bf16(al[kc], b1h, acc1, 0, 0, 0);
            }
            int col0 = j0 + (cp * 2 + 0) * 32 + lrow;
            int col1 = j0 + (cp * 2 + 1) * 32 + lrow;
            float h20 = h2c + ((use_prev ? hvec[col0] : 0.f) - colnorm[col0]) * se;
            float h21 = h2c + ((use_prev ? hvec[col1] : 0.f) - colnorm[col1]) * se;
#pragma unroll
            for (int r = 0; r < 16; ++r) {
                float s0 = fmaf(acc0[r], se, h20);
                float s1 = fmaf(acc1[r], se, h21);
                float mn = fmaxf(fmaxf(m[r], s0), s1);
                l[r] = fmaf(l[r], exp2f(m[r] - mn),
                            exp2f(s0 - mn) + exp2f(s1 - mn));
                m[r] = mn;
            }
        }
    }

    // ---- merge the 32 col-lanes sharing each row (lhalf preserved)
#pragma unroll
    for (int off = 1; off < 32; off <<= 1) {
#pragma unroll
        for (int r = 0; r < 16; ++r) {
            float mo = __shfl_xor(m[r], off);
            float lo = __shfl_xor(l[r], off);
            float mn = fmaxf(m[r], mo);
            l[r] = l[r] * exp2f(m[r] - mn) + lo * exp2f(mo - mn);
            m[r] = mn;
        }
    }

    if (lrow == 0) {
        const float epsln2 = eps * LN2_F;
#pragma unroll
        for (int r = 0; r < 16; ++r) {
            int row = (r & 3) + 8 * (r >> 2) + 4 * lhalf;  // C/D mapping (m74/m101)
            int i = i0 + wave * 32 + row;
            float f = rownorm[i] - epsln2 * (m[r] + log2f(l[r]));
            if (do_avg) f = 0.5f * (avgvec[i] + f);
            outvec[i] = f;
        }
    }
}

// loss = [ sum_{b,i} (f_ba - f_aa) + (g_ab - g_bb) ] / (N*B)
__global__ __launch_bounds__(256) void reduce_kernel(const float* __restrict__ fin,
                                                     float* __restrict__ out) {
    float s = 0.f;
    for (int idx = threadIdx.x; idx < 4 * 4 * NPTS; idx += 256) {
        int mat = idx >> 14;
        float v = fin[idx];
        s += (mat < 2) ? v : -v;
    }
#pragma unroll
    for (int off = 32; off > 0; off >>= 1) s += __shfl_down(s, off);
    __shared__ float red[4];
    if ((threadIdx.x & 63) == 0) red[threadIdx.x >> 6] = s;
    __syncthreads();
    if (threadIdx.x == 0) {
        float t = red[0] + red[1] + red[2] + red[3];
        out[0] = t * (1.0f / (4096.0f * 4.0f));
    }
}

extern "C" void kernel_launch(void* const* d_in, const int* in_sizes, int n_in,
                              void* d_out, int out_size, void* d_ws, size_t ws_size,
                              hipStream_t stream) {
    const float* x = (const float*)d_in[0];
    const float* y = (const float*)d_in[1];
    float* out = (float*)d_out;

    float* norms = (float*)d_ws;          // 32768 floats
    float* bufA  = norms + 32768;         // 65536 floats: [mat][b][i]
    float* bufB  = bufA + 65536;          // 65536 floats

    // eps schedule: exp(arange(2*ln16, 2*ln0.05, 2*ln0.9)) ++ [0.05^2]
    const double start = 2.0 * log(16.0);
    const double stop  = 2.0 * log(0.05);
    const double step  = 2.0 * log(0.9);
    float eps_list[64];
    int ne = 0;
    for (int k = 0;; ++k) {
        double e = start + k * step;
        if (!(e > stop)) break;
        eps_list[ne++] = (float)exp(e);
    }
    eps_list[ne++] = (float)(0.05 * 0.05);   // 56 entries

    norms_kernel<<<128, 256, 0, stream>>>(x, y, norms);

    // init at eps0 (no prev potentials, no averaging)
    softmin_kernel<<<512, 256, 0, stream>>>(x, y, norms, bufB, bufA,
                                            eps_list[0], 0, 0);
    float* prev = bufA;
    float* next = bufB;
    for (int t = 0; t < ne; ++t) {
        softmin_kernel<<<512, 256, 0, stream>>>(x, y, norms, prev, next,
                                                eps_list[t], 1, 1);
        float* tmp = prev; prev = next; next = tmp;
    }
    // final extrapolation at eps = blur^p, no averaging
    softmin_kernel<<<512, 256, 0, stream>>>(x, y, norms, prev, next,
                                            eps_list[ne - 1], 1, 0);

    reduce_kernel<<<1, 256, 0, stream>>>(next, out);
}

// Round 3
// 9325.299 us; speedup vs baseline: 3.1555x; 1.2350x over previous
//
#include <hip/hip_runtime.h>
#include <cmath>

#define NPTS 4096
#define LOG2E_F 1.4426950408889634f
#define LN2_F   0.6931471805599453f
#define BLOG_F  -8.31776616671934f   /* -ln(4096) */

typedef __attribute__((ext_vector_type(8)))  short s16x8;
typedef __attribute__((ext_vector_type(16))) float f32x16;

#define GAS __attribute__((address_space(1)))
#define LAS __attribute__((address_space(3)))

__device__ __forceinline__ ushort bf16h(float f) {
    uint u = __float_as_uint(f);
    return (ushort)((u + 0x7fffu + ((u >> 16) & 1u)) >> 16);
}
__device__ __forceinline__ float bf16tof(ushort h) {
    return __uint_as_float(((uint)h) << 16);
}

// Prepass: split x,y into bf16 hi/lo, stored point-major with XOR-swizzled
// 16B chunks:  split[(which*4+b)*4096 + n][chunk t' = t ^ (n&7)][8 comps]
// hi chunks t=0..7 (comps 8t..8t+7), lo chunks t=8..15. Also 0.5*|p|^2 norms.
__global__ __launch_bounds__(256) void split_kernel(const float* __restrict__ x,
                                                    const float* __restrict__ y,
                                                    float* __restrict__ norms,
                                                    ushort* __restrict__ split) {
    int flat = blockIdx.x * 256 + threadIdx.x;   // 0..32767
    int which = flat >> 14;
    int b = (flat >> 12) & 3;
    int n = flat & 4095;
    const float* src = (which ? y : x) + (size_t)b * 64 * NPTS + n;
    ushort* dst = split + ((size_t)(which * 4 + b) * NPTS + n) * 128;
    const int sw = n & 7;
    float s = 0.f;
#pragma unroll
    for (int t = 0; t < 8; ++t) {
        float v[8]; ushort hh[8], ll[8];
#pragma unroll
        for (int e = 0; e < 8; ++e) {
            v[e] = src[(size_t)(t * 8 + e) * NPTS];
            s += v[e] * v[e];
            hh[e] = bf16h(v[e]);
            ll[e] = bf16h(v[e] - bf16tof(hh[e]));
        }
        uint4 hw, lw;
        hw.x = (uint)hh[0] | ((uint)hh[1] << 16);
        hw.y = (uint)hh[2] | ((uint)hh[3] << 16);
        hw.z = (uint)hh[4] | ((uint)hh[5] << 16);
        hw.w = (uint)hh[6] | ((uint)hh[7] << 16);
        lw.x = (uint)ll[0] | ((uint)ll[1] << 16);
        lw.y = (uint)ll[2] | ((uint)ll[3] << 16);
        lw.z = (uint)ll[4] | ((uint)ll[5] << 16);
        lw.w = (uint)ll[6] | ((uint)ll[7] << 16);
        *(uint4*)&dst[(size_t)((t ^ sw) * 8)]       = hw;
        *(uint4*)&dst[(size_t)(((t ^ sw) + 8) * 8)] = lw;   // (t+8)^sw == (t^sw)+8
    }
    norms[flat] = 0.5f * s;
}

// One annealing phase. acc = C-init + x.y where C-init = eps*blog + g_j - yn_j,
// so s_nat = acc/eps; flash update in acc units, f = xn_i - m - eps*ln2*log2(l).
__global__ __launch_bounds__(256, 2) void softmin_kernel(
    const ushort* __restrict__ split, const float* __restrict__ norms,
    const float* __restrict__ prev, float* __restrict__ next,
    float eps, int use_prev, int do_avg)
{
    __shared__ __align__(16) ushort Bt[128 * 128];   // 32 KB, swizzled 256B rows

    const int tid   = threadIdx.x;
    const int bid   = blockIdx.x;
    const int b     = bid & 3;           // round-robin XCD -> constant batch/XCD
    const int mat   = (bid >> 2) & 3;
    const int itile = bid >> 4;          // 0..31

    const int row_is_x = (mat == 0 || mat == 2);
    const int col_is_x = (mat == 1 || mat == 2);
    const ushort* rowsplit = split + (size_t)((row_is_x ? 0 : 4) + b) * NPTS * 128;
    const ushort* colsplit = split + (size_t)((col_is_x ? 0 : 4) + b) * NPTS * 128;
    const float* rownorm = norms + (row_is_x ? 0 : 16384) + b * NPTS;
    const float* colnorm = norms + (col_is_x ? 0 : 16384) + b * NPTS;
    const int hmat = (mat == 0) ? 1 : ((mat == 1) ? 0 : mat);
    const float* hvec   = prev + (size_t)(hmat * 4 + b) * NPTS;
    const float* avgvec = prev + (size_t)(mat  * 4 + b) * NPTS;
    float*       outvec = next + (size_t)(mat  * 4 + b) * NPTS;

    const float se      = (1.0f / eps) * LOG2E_F;
    const float epsblog = eps * BLOG_F;

    const int wave  = tid >> 6;
    const int lane  = tid & 63;
    const int lrow  = lane & 31;
    const int lhalf = lane >> 5;
    const int i0    = itile * 128;
    const int arow  = i0 + wave * 32 + lrow;

    // ---- A fragments (hi/lo), once per block, pre-split in global
    s16x8 ah[4], al[4];
    const int asw = arow & 7;
#pragma unroll
    for (int kc = 0; kc < 4; ++kc) {
        int th = (kc * 2 + lhalf) ^ asw;
        ah[kc] = *(const s16x8*)&rowsplit[(size_t)arow * 128 + th * 8];
        al[kc] = *(const s16x8*)&rowsplit[(size_t)arow * 128 + (th + 8) * 8];
    }

    float m[16], l[16];
#pragma unroll
    for (int r = 0; r < 16; ++r) { m[r] = -__builtin_inff(); l[r] = 0.f; }

    for (int jt = 0; jt < 32; ++jt) {
        const int j0 = jt * 128;

        // per-col C-init values for this j-tile (4 col-tiles)
        float hp[4];
#pragma unroll
        for (int t = 0; t < 4; ++t) {
            int jc = j0 + t * 32 + lrow;
            float g = use_prev ? hvec[jc] : 0.f;
            hp[t] = epsblog + g - colnorm[jc];
        }

        __syncthreads();   // previous tile's readers done
        {
            const ushort* gsrc = colsplit + (size_t)j0 * 128;
#pragma unroll
            for (int it = 0; it < 8; ++it) {
                int q = it * 256 + tid;    // 16B chunk id; wave-uniform base + lane*16
                __builtin_amdgcn_global_load_lds(
                    (const GAS uint*)(gsrc + q * 8),
                    (LAS uint*)(&Bt[q * 8]), 16, 0, 0);
            }
        }
        __syncthreads();   // staging complete (vmcnt drained by barrier)

        f32x16 acc[4];
#pragma unroll
        for (int t = 0; t < 4; ++t)
#pragma unroll
            for (int r = 0; r < 16; ++r) acc[t][r] = hp[t];

#pragma unroll
        for (int kc = 0; kc < 4; ++kc) {
            const int thb = kc * 2 + lhalf;
#pragma unroll
            for (int t = 0; t < 4; ++t) {
                const int p = t * 32 + lrow;
                const int tb = thb ^ (p & 7);
                s16x8 bh = *(const s16x8*)&Bt[p * 128 + tb * 8];
                s16x8 bl = *(const s16x8*)&Bt[p * 128 + (tb + 8) * 8];
                acc[t] = __builtin_amdgcn_mfma_f32_32x32x16_bf16(ah[kc], bh, acc[t], 0, 0, 0);
                acc[t] = __builtin_amdgcn_mfma_f32_32x32x16_bf16(ah[kc], bl, acc[t], 0, 0, 0);
                acc[t] = __builtin_amdgcn_mfma_f32_32x32x16_bf16(al[kc], bh, acc[t], 0, 0, 0);
            }
        }

        // flash update, 4 cols per row-register per j-tile
#pragma unroll
        for (int r = 0; r < 16; ++r) {
            float a0 = acc[0][r], a1 = acc[1][r];
            float a2 = acc[2][r], a3 = acc[3][r];
            float tm = fmaxf(fmaxf(a0, a1), fmaxf(a2, a3));
            float mn = fmaxf(m[r], tm);
            float tt = -se * mn;
            float e0 = exp2f(fmaf(a0, se, tt));
            float e1 = exp2f(fmaf(a1, se, tt));
            float e2 = exp2f(fmaf(a2, se, tt));
            float e3 = exp2f(fmaf(a3, se, tt));
            float rs = exp2f(fmaf(m[r], se, tt));
            l[r] = fmaf(l[r], rs, (e0 + e1) + (e2 + e3));
            m[r] = mn;
        }
    }

    // merge the 32 col-lanes sharing each row
#pragma unroll
    for (int off = 1; off < 32; off <<= 1) {
#pragma unroll
        for (int r = 0; r < 16; ++r) {
            float mo = __shfl_xor(m[r], off);
            float lo = __shfl_xor(l[r], off);
            float mn = fmaxf(m[r], mo);
            float tt = -se * mn;
            l[r] = fmaf(l[r], exp2f(fmaf(m[r], se, tt)),
                        lo * exp2f(fmaf(mo, se, tt)));
            m[r] = mn;
        }
    }

    if (lrow == 0) {
        const float epsln2 = eps * LN2_F;
#pragma unroll
        for (int r = 0; r < 16; ++r) {
            int row = (r & 3) + 8 * (r >> 2) + 4 * lhalf;   // 32x32 C/D map (m74/m101)
            int i = i0 + wave * 32 + row;
            float f = rownorm[i] - m[r] - epsln2 * log2f(l[r]);
            if (do_avg) f = 0.5f * (avgvec[i] + f);
            outvec[i] = f;
        }
    }
}

// loss = [ sum_{b,i} (f_ba - f_aa) + (g_ab - g_bb) ] / (N*B)
__global__ __launch_bounds__(256) void reduce_kernel(const float* __restrict__ fin,
                                                     float* __restrict__ out) {
    float s = 0.f;
    for (int idx = threadIdx.x; idx < 4 * 4 * NPTS; idx += 256) {
        int mat = idx >> 14;
        float v = fin[idx];
        s += (mat < 2) ? v : -v;
    }
#pragma unroll
    for (int off = 32; off > 0; off >>= 1) s += __shfl_down(s, off);
    __shared__ float red[4];
    if ((threadIdx.x & 63) == 0) red[threadIdx.x >> 6] = s;
    __syncthreads();
    if (threadIdx.x == 0) {
        float t = red[0] + red[1] + red[2] + red[3];
        out[0] = t * (1.0f / (4096.0f * 4.0f));
    }
}

extern "C" void kernel_launch(void* const* d_in, const int* in_sizes, int n_in,
                              void* d_out, int out_size, void* d_ws, size_t ws_size,
                              hipStream_t stream) {
    const float* x = (const float*)d_in[0];
    const float* y = (const float*)d_in[1];
    float* out = (float*)d_out;

    float* norms = (float*)d_ws;            // 32768 floats
    float* bufA  = norms + 32768;           // 65536 floats: [mat][b][i]
    float* bufB  = bufA + 65536;            // 65536 floats
    ushort* split = (ushort*)(bufB + 65536); // 2*4*4096*128 ushorts = 8 MB

    // eps schedule: exp(arange(2*ln16, 2*ln0.05, 2*ln0.9)) ++ [0.05^2]
    const double start = 2.0 * log(16.0);
    const double stop  = 2.0 * log(0.05);
    const double step  = 2.0 * log(0.9);
    float eps_list[64];
    int ne = 0;
    for (int k = 0;; ++k) {
        double e = start + k * step;
        if (!(e > stop)) break;
        eps_list[ne++] = (float)exp(e);
    }
    eps_list[ne++] = (float)(0.05 * 0.05);   // 56 entries

    split_kernel<<<128, 256, 0, stream>>>(x, y, norms, split);

    // init at eps0 (no prev potentials, no averaging)
    softmin_kernel<<<512, 256, 0, stream>>>(split, norms, bufB, bufA,
                                            eps_list[0], 0, 0);
    float* prev = bufA;
    float* next = bufB;
    for (int t = 0; t < ne; ++t) {
        softmin_kernel<<<512, 256, 0, stream>>>(split, norms, prev, next,
                                                eps_list[t], 1, 1);
        float* tmp = prev; prev = next; next = tmp;
    }
    // final extrapolation at eps = blur^p, no averaging
    softmin_kernel<<<512, 256, 0, stream>>>(split, norms, prev, next,
                                            eps_list[ne - 1], 1, 0);

    reduce_kernel<<<1, 256, 0, stream>>>(next, out);
}